// Round 2
// baseline (369.300 us; speedup 1.0000x reference)
//
#include <hip/hip_runtime.h>
#include <hip/hip_bf16.h>
#include <stdint.h>

// Problem (all fp32 I/O): out[m,o] = sum_k x[m,k] * qw[o,k] + bias[o]
//   qw = ternarize(weight): scale_o = max(max_k |w[o,k]|, 1e-6);
//   t = (w/scale > .5 ? 1 : w/scale < -.5 ? -1 : 0); qw = t*scale.
// Ternary t exact in bf16; scale fp32 in GEMM epilogue.
// M=16384, N=2048, K=2048.
//
// Pass C: 256x256 8-phase schedule with PINNED wait discipline (m201):
//   per phase: [reads] [eager lgkmcnt(8) if 12 reads] sched_barrier
//              s_barrier; lgkmcnt(0); sched_barrier; setprio(1);
//              16 pure MFMA; setprio(0); sched_barrier; s_barrier.
//   counted vmcnt(8) only at tile boundary (8 loads/thread = 1 tile in flight).

#define M_DIM 16384
#define N_DIM 2048
#define K_DIM 2048

#define BM 256
#define BN 256
#define BK 64
#define NT (K_DIM / BK)  // 32 K-tiles

typedef __bf16 bf16x8 __attribute__((ext_vector_type(8)));
typedef float f32x4 __attribute__((ext_vector_type(4)));

// ---------------------------------------------------------------------------
// Pass A: x fp32 -> bf16. 8 elements/thread, float4 loads, 16 B store.
// ---------------------------------------------------------------------------
__global__ __launch_bounds__(256) void cvt_x_k(
    const float* __restrict__ x, __hip_bfloat16* __restrict__ xb) {
  const size_t i = ((size_t)blockIdx.x * 256 + threadIdx.x) * 8;
  const float4 a = *(const float4*)(x + i);
  const float4 b = *(const float4*)(x + i + 4);
  bf16x8 o;
  o[0] = (__bf16)a.x; o[1] = (__bf16)a.y; o[2] = (__bf16)a.z; o[3] = (__bf16)a.w;
  o[4] = (__bf16)b.x; o[5] = (__bf16)b.y; o[6] = (__bf16)b.z; o[7] = (__bf16)b.w;
  *(bf16x8*)((__bf16*)xb + i) = o;
}

// ---------------------------------------------------------------------------
// Pass B: per-row ternarize (fp32 in, bf16 ternary out, fp32 scale).
// ---------------------------------------------------------------------------
__global__ __launch_bounds__(256) void ternarize_k(
    const float* __restrict__ w,
    __hip_bfloat16* __restrict__ qw,
    float* __restrict__ scales) {
  const int row = blockIdx.x;
  const float* wr = w + (size_t)row * K_DIM;

  float m = 0.0f;
  for (int k = threadIdx.x; k < K_DIM; k += 256)
    m = fmaxf(m, fabsf(wr[k]));

  for (int off = 32; off > 0; off >>= 1)
    m = fmaxf(m, __shfl_down(m, off, 64));
  __shared__ float wmax[4];
  if ((threadIdx.x & 63) == 0) wmax[threadIdx.x >> 6] = m;
  __syncthreads();
  float scale = fmaxf(fmaxf(wmax[0], wmax[1]), fmaxf(wmax[2], wmax[3]));
  scale = fmaxf(scale, 1e-6f);
  if (threadIdx.x == 0) scales[row] = scale;

  for (int k = threadIdx.x; k < K_DIM; k += 256) {
    const float v = wr[k] / scale;  // identical fp32 op to the reference
    const float t = (v > 0.5f) ? 1.0f : ((v < -0.5f) ? -1.0f : 0.0f);
    qw[(size_t)row * K_DIM + k] = __float2bfloat16(t);
  }
}

// ---------------------------------------------------------------------------
// Pass C: 256x256 8-phase bf16 MFMA GEMM, pinned-wait schedule.
// ---------------------------------------------------------------------------
static __device__ __forceinline__ void gload16(const __hip_bfloat16* g,
                                               char* l) {
  // LDS dest is wave-uniform base; HW adds lane*16.
  __builtin_amdgcn_global_load_lds(
      (__attribute__((address_space(1))) void*)const_cast<__hip_bfloat16*>(g),
      (__attribute__((address_space(3))) void*)(l), 16, 0, 0);
}

#define MFMA_(d, a, b) \
  d = __builtin_amdgcn_mfma_f32_16x16x32_bf16(a, b, d, 0, 0, 0)

#define SBAR()  __builtin_amdgcn_s_barrier()
#define SCHED() __builtin_amdgcn_sched_barrier(0)
#define LGKM0() do { asm volatile("s_waitcnt lgkmcnt(0)" ::: "memory"); SCHED(); } while (0)

__global__ __launch_bounds__(512, 2) void gemm_bt_k(
    const __hip_bfloat16* __restrict__ A,   // xb [M,K] bf16
    const __hip_bfloat16* __restrict__ B,   // qw [N,K] bf16 ternary
    const float* __restrict__ scales,       // [N]
    const float* __restrict__ bias,         // [N]
    float* __restrict__ C) {                // [M,N] fp32
  // LDS map (bytes): buf(t&1)*65536 + { A: half*16384 | B: 32768 + half*16384 }
  // Physical chunk p (16 B) at p*16; p = row*8 + pc; data there is logical
  // column (pc ^ (row&7)) of that row (source-side swizzle); reads XOR back.
  __shared__ __align__(128) char lds[131072];

  const int tid  = threadIdx.x;
  const int wave = tid >> 6;
  const int lane = tid & 63;
  const int quad = lane >> 4;
  const int lrow = lane & 15;
  const int wr = wave >> 2;  // 0..1 (M)
  const int wc = wave & 3;   // 0..3 (N)

  // T1: XCD swizzle. 512 blocks = 8 XCDs x 64; each XCD gets an 8x8 supertile.
  const int orig = blockIdx.x;
  const int wg = (orig & 7) * 64 + (orig >> 3);
  const int bx = wg & 7;   // N blocks (8)
  const int by = wg >> 3;  // M blocks (64)
  const int m0 = by * BM;
  const int n0 = bx * BN;

  // ---- staging addresses (this thread stages rows srow+{0,64,128,192}) ----
  const int srow  = tid >> 3;                 // 0..63
  const int scol8 = (tid & 7) ^ (srow & 7);   // inverse-swizzled source chunk
  const __hip_bfloat16* Ag = A + (size_t)(m0 + srow) * K_DIM + scol8 * 8;
  const __hip_bfloat16* Bg = B + (size_t)(n0 + srow) * K_DIM + scol8 * 8;
  const int sbase = wave * 1024;  // wave-uniform chunk base within a half

  // ---- fragment-read integer offsets (tile-invariant) ----
  const int axor = lrow & 7;
  const int cs0 = ((0 + quad) ^ axor) * 16;   // k-half 0 chunk byte
  const int cs1 = ((4 + quad) ^ axor) * 16;   // k-half 1 chunk byte
  const int aHalf = wr * 16384;
  const int bHalf = 32768 + (wc >> 1) * 16384;
  const int bRow  = (wc & 1) * 64 + lrow;
  const int oA0 = aHalf + lrow * 128 + cs0;
  const int oA1 = aHalf + lrow * 128 + cs1;
  const int oB0 = bHalf + bRow * 128 + cs0;
  const int oB1 = bHalf + bRow * 128 + cs1;

  auto STAGE_A = [&](int dst, int kk) {
    const __hip_bfloat16* g = Ag + kk;
    gload16(g,               lds + dst);
    gload16(g +  64 * K_DIM, lds + dst + 8192);
    gload16(g + 128 * K_DIM, lds + dst + 16384);
    gload16(g + 192 * K_DIM, lds + dst + 24576);
  };
  auto STAGE_B = [&](int dst, int kk) {
    const __hip_bfloat16* g = Bg + kk;
    gload16(g,               lds + dst + 32768);
    gload16(g +  64 * K_DIM, lds + dst + 40960);
    gload16(g + 128 * K_DIM, lds + dst + 49152);
    gload16(g + 192 * K_DIM, lds + dst + 57344);
  };

  f32x4 acc[8][4] = {};

  // ---- prologue: stage tiles 0 (buf0) and 1 (buf1); wait tile 0 only ----
  STAGE_A(sbase, 0);          STAGE_B(sbase, 0);
  STAGE_A(sbase + 65536, BK); STAGE_B(sbase + 65536, BK);
  asm volatile("s_waitcnt vmcnt(8)" ::: "memory");  // tile 0 landed
  SBAR();

  for (int t = 0; t < NT; ++t) {
    const int bo  = (t & 1) << 16;
    const int kk2 = (t + 2) * BK;
    const bool pf = (t + 2) < NT;
    const int aB0 = bo + oA0, aB1 = bo + oA1;
    const int bB0 = bo + oB0, bB1 = bo + oB1;

    bf16x8 af0[4][2], af1[4][2], bf0[2][2], bf1[2][2];

    // ---- P1: read af[0-3] + bf[0-1] (12); MFMA quadrant (m0-3, n0-1) ----
#pragma unroll
    for (int m = 0; m < 4; ++m) {
      af0[m][0] = *(const bf16x8*)(lds + aB0 + m * 2048);
      af0[m][1] = *(const bf16x8*)(lds + aB1 + m * 2048);
    }
#pragma unroll
    for (int n = 0; n < 2; ++n) {
      bf0[n][0] = *(const bf16x8*)(lds + bB0 + n * 2048);
      bf0[n][1] = *(const bf16x8*)(lds + bB1 + n * 2048);
    }
    asm volatile("s_waitcnt lgkmcnt(8)" ::: "memory");  // eager pre-drain
    SCHED();
    SBAR();
    LGKM0();
    __builtin_amdgcn_s_setprio(1);
#pragma unroll
    for (int m = 0; m < 4; ++m)
#pragma unroll
      for (int n = 0; n < 2; ++n) {
        MFMA_(acc[m][n], af0[m][0], bf0[n][0]);
        MFMA_(acc[m][n], af0[m][1], bf0[n][1]);
      }
    __builtin_amdgcn_s_setprio(0);
    SCHED();
    SBAR();

    // ---- P2: read af[4-7] (8); MFMA quadrant (m4-7, n0-1) ----
#pragma unroll
    for (int m = 0; m < 4; ++m) {
      af1[m][0] = *(const bf16x8*)(lds + aB0 + (m + 4) * 2048);
      af1[m][1] = *(const bf16x8*)(lds + aB1 + (m + 4) * 2048);
    }
    SCHED();
    SBAR();
    LGKM0();
    __builtin_amdgcn_s_setprio(1);
#pragma unroll
    for (int m = 0; m < 4; ++m)
#pragma unroll
      for (int n = 0; n < 2; ++n) {
        MFMA_(acc[m + 4][n], af1[m][0], bf0[n][0]);
        MFMA_(acc[m + 4][n], af1[m][1], bf0[n][1]);
      }
    __builtin_amdgcn_s_setprio(0);
    SCHED();
    SBAR();

    // ---- P3: stage A of tile t+2 (A reads drained at P2 entry, barrier'd);
    //          read bf[2-3] (4); MFMA quadrant (m4-7, n2-3) ----
    if (pf) STAGE_A(bo + sbase, kk2);
#pragma unroll
    for (int n = 0; n < 2; ++n) {
      bf1[n][0] = *(const bf16x8*)(lds + bB0 + (n + 2) * 2048);
      bf1[n][1] = *(const bf16x8*)(lds + bB1 + (n + 2) * 2048);
    }
    SCHED();
    SBAR();
    LGKM0();
    __builtin_amdgcn_s_setprio(1);
#pragma unroll
    for (int m = 0; m < 4; ++m)
#pragma unroll
      for (int n = 0; n < 2; ++n) {
        MFMA_(acc[m + 4][n + 2], af1[m][0], bf1[n][0]);
        MFMA_(acc[m + 4][n + 2], af1[m][1], bf1[n][1]);
      }
    __builtin_amdgcn_s_setprio(0);
    SCHED();
    SBAR();

    // ---- P4: stage B of tile t+2 (B reads drained at P3 entry, barrier'd);
    //          MFMA quadrant (m0-3, n2-3); counted boundary wait ----
    if (pf) STAGE_B(bo + sbase, kk2);
    SCHED();
    SBAR();
    __builtin_amdgcn_s_setprio(1);
#pragma unroll
    for (int m = 0; m < 4; ++m)
#pragma unroll
      for (int n = 0; n < 2; ++n) {
        MFMA_(acc[m][n + 2], af0[m][0], bf1[n][0]);
        MFMA_(acc[m][n + 2], af0[m][1], bf1[n][1]);
      }
    __builtin_amdgcn_s_setprio(0);
    SCHED();
    // Tile t+1 must be landed for the next P1. Newer-than-t+1 = the 8 loads
    // for tile t+2 issued this tile -> vmcnt(8); drain at the tail.
    if (t < NT - 2)
      asm volatile("s_waitcnt vmcnt(8)" ::: "memory");
    else
      asm volatile("s_waitcnt vmcnt(0)" ::: "memory");
    SBAR();
  }

  // ---- epilogue: C = acc*scale[col] + bias[col] ----
  // C/D layout (16x16x32 bf16): col = lane&15, row = quad*4 + reg.
#pragma unroll
  for (int n = 0; n < 4; ++n) {
    const int col = n0 + wc * 64 + n * 16 + lrow;
    const float s = scales[col];
    const float b = bias[col];
#pragma unroll
    for (int m = 0; m < 8; ++m) {
      const int rbase = m0 + wr * 128 + m * 16 + quad * 4;
#pragma unroll
      for (int r = 0; r < 4; ++r)
        C[(size_t)(rbase + r) * N_DIM + col] = acc[m][n][r] * s + b;
    }
  }
}

extern "C" void kernel_launch(void* const* d_in, const int* in_sizes, int n_in,
                              void* d_out, int out_size, void* d_ws, size_t ws_size,
                              hipStream_t stream) {
  const float* x    = (const float*)d_in[0];  // [4,4096,2048] fp32
  const float* w    = (const float*)d_in[1];  // [2048,2048]   fp32
  const float* bias = (const float*)d_in[2];  // [2048]        fp32
  float* out = (float*)d_out;                 // [16384,2048]  fp32

  // ws layout: xb bf16 [M*K] (64 MiB) | qw bf16 [N*K] (8 MiB) | scales fp32 [N]
  __hip_bfloat16* xb = (__hip_bfloat16*)d_ws;
  __hip_bfloat16* qw = (__hip_bfloat16*)((char*)d_ws + (size_t)M_DIM * K_DIM * 2);
  float* scales = (float*)((char*)d_ws + (size_t)M_DIM * K_DIM * 2 + (size_t)N_DIM * K_DIM * 2);

  cvt_x_k<<<dim3((M_DIM * (size_t)K_DIM) / (256 * 8)), dim3(256), 0, stream>>>(x, xb);
  ternarize_k<<<dim3(N_DIM), dim3(256), 0, stream>>>(w, qw, scales);
  gemm_bt_k<<<dim3((M_DIM / BM) * (N_DIM / BN)), dim3(512), 0, stream>>>(xb, qw, scales, bias, out);
}

// Round 3
// 355.306 us; speedup vs baseline: 1.0394x; 1.0394x over previous
//
#include <hip/hip_runtime.h>
#include <hip/hip_bf16.h>
#include <stdint.h>

// Problem (all fp32 I/O): out[m,o] = sum_k x[m,k] * qw[o,k] + bias[o]
//   qw = ternarize(weight): scale_o = max(max_k |w[o,k]|, 1e-6);
//   t = (w/scale > .5 ? 1 : w/scale < -.5 ? -1 : 0); qw = t*scale.
// Ternary t exact in bf16; scale fp32 in GEMM epilogue.
// M=16384, N=2048, K=2048.
//
// Pass C: 256x256 tile, BK=64, 8 waves. THIN-BARRIER schedule: only the 3
// correctness-required barriers per K-tile (not 8 lockstep ones):
//   B1 after last A-read  -> STAGE_A(t+2) WAR-safe
//   B2 after last B-read  -> STAGE_B(t+2) WAR-safe
//   B3 after counted vmcnt(8) -> cross-wave RAW on staged tile t+1
// Waves drift between barriers so ds_reads of one wave overlap MFMA bursts
// of others (cross-wave pipelining). setprio(1) around MFMA clusters now has
// wave role-diversity to arbitrate (T5 mechanism).

#define M_DIM 16384
#define N_DIM 2048
#define K_DIM 2048

#define BM 256
#define BN 256
#define BK 64
#define NT (K_DIM / BK)  // 32 K-tiles

typedef __bf16 bf16x8 __attribute__((ext_vector_type(8)));
typedef float f32x4 __attribute__((ext_vector_type(4)));

// ---------------------------------------------------------------------------
// Pass A: x fp32 -> bf16. 8 elements/thread, float4 loads, 16 B store.
// ---------------------------------------------------------------------------
__global__ __launch_bounds__(256) void cvt_x_k(
    const float* __restrict__ x, __hip_bfloat16* __restrict__ xb) {
  const size_t i = ((size_t)blockIdx.x * 256 + threadIdx.x) * 8;
  const float4 a = *(const float4*)(x + i);
  const float4 b = *(const float4*)(x + i + 4);
  bf16x8 o;
  o[0] = (__bf16)a.x; o[1] = (__bf16)a.y; o[2] = (__bf16)a.z; o[3] = (__bf16)a.w;
  o[4] = (__bf16)b.x; o[5] = (__bf16)b.y; o[6] = (__bf16)b.z; o[7] = (__bf16)b.w;
  *(bf16x8*)((__bf16*)xb + i) = o;
}

// ---------------------------------------------------------------------------
// Pass B: per-row ternarize (fp32 in, bf16 ternary out, fp32 scale).
// ---------------------------------------------------------------------------
__global__ __launch_bounds__(256) void ternarize_k(
    const float* __restrict__ w,
    __hip_bfloat16* __restrict__ qw,
    float* __restrict__ scales) {
  const int row = blockIdx.x;
  const float* wr = w + (size_t)row * K_DIM;

  float m = 0.0f;
  for (int k = threadIdx.x; k < K_DIM; k += 256)
    m = fmaxf(m, fabsf(wr[k]));

  for (int off = 32; off > 0; off >>= 1)
    m = fmaxf(m, __shfl_down(m, off, 64));
  __shared__ float wmax[4];
  if ((threadIdx.x & 63) == 0) wmax[threadIdx.x >> 6] = m;
  __syncthreads();
  float scale = fmaxf(fmaxf(wmax[0], wmax[1]), fmaxf(wmax[2], wmax[3]));
  scale = fmaxf(scale, 1e-6f);
  if (threadIdx.x == 0) scales[row] = scale;

  for (int k = threadIdx.x; k < K_DIM; k += 256) {
    const float v = wr[k] / scale;  // identical fp32 op to the reference
    const float t = (v > 0.5f) ? 1.0f : ((v < -0.5f) ? -1.0f : 0.0f);
    qw[(size_t)row * K_DIM + k] = __float2bfloat16(t);
  }
}

// ---------------------------------------------------------------------------
// Pass C: 256x256 bf16 MFMA GEMM, thin-barrier schedule.
// ---------------------------------------------------------------------------
static __device__ __forceinline__ void gload16(const __hip_bfloat16* g,
                                               char* l) {
  // LDS dest is wave-uniform base; HW adds lane*16.
  __builtin_amdgcn_global_load_lds(
      (__attribute__((address_space(1))) void*)const_cast<__hip_bfloat16*>(g),
      (__attribute__((address_space(3))) void*)(l), 16, 0, 0);
}

#define MFMA_(d, a, b) \
  d = __builtin_amdgcn_mfma_f32_16x16x32_bf16(a, b, d, 0, 0, 0)

#define SBAR()  __builtin_amdgcn_s_barrier()
#define SCHED() __builtin_amdgcn_sched_barrier(0)
#define CFENCE() asm volatile("" ::: "memory")

__global__ __launch_bounds__(512, 2) void gemm_bt_k(
    const __hip_bfloat16* __restrict__ A,   // xb [M,K] bf16
    const __hip_bfloat16* __restrict__ B,   // qw [N,K] bf16 ternary
    const float* __restrict__ scales,       // [N]
    const float* __restrict__ bias,         // [N]
    float* __restrict__ C) {                // [M,N] fp32
  // LDS map (bytes): buf(t&1)*65536 + { A: half*16384 | B: 32768 + half*16384 }
  // Physical chunk p (16 B) at p*16; p = row*8 + pc; data there is logical
  // column (pc ^ (row&7)) of that row (source-side swizzle); reads XOR back.
  __shared__ __align__(128) char lds[131072];

  const int tid  = threadIdx.x;
  const int wave = tid >> 6;
  const int lane = tid & 63;
  const int quad = lane >> 4;
  const int lrow = lane & 15;
  const int wr = wave >> 2;  // 0..1 (M)
  const int wc = wave & 3;   // 0..3 (N)

  // T1: XCD swizzle. 512 blocks = 8 XCDs x 64; each XCD gets an 8x8 supertile.
  const int orig = blockIdx.x;
  const int wg = (orig & 7) * 64 + (orig >> 3);
  const int bx = wg & 7;   // N blocks (8)
  const int by = wg >> 3;  // M blocks (64)
  const int m0 = by * BM;
  const int n0 = bx * BN;

  // ---- staging addresses (this thread stages rows srow+{0,64,128,192}) ----
  const int srow  = tid >> 3;                 // 0..63
  const int scol8 = (tid & 7) ^ (srow & 7);   // inverse-swizzled source chunk
  const __hip_bfloat16* Ag = A + (size_t)(m0 + srow) * K_DIM + scol8 * 8;
  const __hip_bfloat16* Bg = B + (size_t)(n0 + srow) * K_DIM + scol8 * 8;
  const int sbase = wave * 1024;  // wave-uniform chunk base within a half

  // ---- fragment-read integer offsets (tile-invariant) ----
  const int axor = lrow & 7;
  const int cs0 = ((0 + quad) ^ axor) * 16;   // k-half 0 chunk byte
  const int cs1 = ((4 + quad) ^ axor) * 16;   // k-half 1 chunk byte
  const int aHalf = wr * 16384;
  const int bHalf = 32768 + (wc >> 1) * 16384;
  const int bRow  = (wc & 1) * 64 + lrow;
  const int oA0 = aHalf + lrow * 128 + cs0;
  const int oA1 = aHalf + lrow * 128 + cs1;
  const int oB0 = bHalf + bRow * 128 + cs0;
  const int oB1 = bHalf + bRow * 128 + cs1;

  auto STAGE_A = [&](int dst, int kk) {
    const __hip_bfloat16* g = Ag + kk;
    gload16(g,               lds + dst);
    gload16(g +  64 * K_DIM, lds + dst + 8192);
    gload16(g + 128 * K_DIM, lds + dst + 16384);
    gload16(g + 192 * K_DIM, lds + dst + 24576);
  };
  auto STAGE_B = [&](int dst, int kk) {
    const __hip_bfloat16* g = Bg + kk;
    gload16(g,               lds + dst + 32768);
    gload16(g +  64 * K_DIM, lds + dst + 40960);
    gload16(g + 128 * K_DIM, lds + dst + 49152);
    gload16(g + 192 * K_DIM, lds + dst + 57344);
  };

  f32x4 acc[8][4] = {};

  // ---- prologue: stage tiles 0 (buf0) and 1 (buf1); wait tile 0 only ----
  STAGE_A(sbase, 0);          STAGE_B(sbase, 0);
  STAGE_A(sbase + 65536, BK); STAGE_B(sbase + 65536, BK);
  asm volatile("s_waitcnt vmcnt(8)" ::: "memory");  // tile 0 landed
  SBAR();

  for (int t = 0; t < NT; ++t) {
    const int bo  = (t & 1) << 16;
    const int kk2 = (t + 2) * BK;
    const bool pf = (t + 2) < NT;
    const int aB0 = bo + oA0, aB1 = bo + oA1;
    const int bB0 = bo + oB0, bB1 = bo + oB1;

    bf16x8 af0[4][2], af1[4][2], bf0[2][2], bf1[2][2];

    // ---- read af0 (m0-3) + bf0 (n0-1); MFMA Q1 (m0-3, n0-1) ----
#pragma unroll
    for (int m = 0; m < 4; ++m) {
      af0[m][0] = *(const bf16x8*)(lds + aB0 + m * 2048);
      af0[m][1] = *(const bf16x8*)(lds + aB1 + m * 2048);
    }
#pragma unroll
    for (int n = 0; n < 2; ++n) {
      bf0[n][0] = *(const bf16x8*)(lds + bB0 + n * 2048);
      bf0[n][1] = *(const bf16x8*)(lds + bB1 + n * 2048);
    }
    __builtin_amdgcn_s_setprio(1);
#pragma unroll
    for (int m = 0; m < 4; ++m)
#pragma unroll
      for (int n = 0; n < 2; ++n) {
        MFMA_(acc[m][n], af0[m][0], bf0[n][0]);
        MFMA_(acc[m][n], af0[m][1], bf0[n][1]);
      }
    __builtin_amdgcn_s_setprio(0);

    // ---- read af1 (m4-7); MFMA Q2 (m4-7, n0-1) ----
#pragma unroll
    for (int m = 0; m < 4; ++m) {
      af1[m][0] = *(const bf16x8*)(lds + aB0 + (m + 4) * 2048);
      af1[m][1] = *(const bf16x8*)(lds + aB1 + (m + 4) * 2048);
    }
    __builtin_amdgcn_s_setprio(1);
#pragma unroll
    for (int m = 0; m < 4; ++m)
#pragma unroll
      for (int n = 0; n < 2; ++n) {
        MFMA_(acc[m + 4][n], af1[m][0], bf0[n][0]);
        MFMA_(acc[m + 4][n], af1[m][1], bf0[n][1]);
      }
    __builtin_amdgcn_s_setprio(0);

    // ---- B1: all A-reads of tile t complete block-wide ----
    SCHED();  // keep the af/bf ds_reads above this barrier
    CFENCE();
    SBAR();
    SCHED();  // keep the stage below the barrier

    // ---- stage A(t+2) into buf(t) A; read bf1 (n2-3); Q3 (m4-7, n2-3) ----
    if (pf) STAGE_A(bo + sbase, kk2);
#pragma unroll
    for (int n = 0; n < 2; ++n) {
      bf1[n][0] = *(const bf16x8*)(lds + bB0 + (n + 2) * 2048);
      bf1[n][1] = *(const bf16x8*)(lds + bB1 + (n + 2) * 2048);
    }
    __builtin_amdgcn_s_setprio(1);
#pragma unroll
    for (int m = 0; m < 4; ++m)
#pragma unroll
      for (int n = 0; n < 2; ++n) {
        MFMA_(acc[m + 4][n + 2], af1[m][0], bf1[n][0]);
        MFMA_(acc[m + 4][n + 2], af1[m][1], bf1[n][1]);
      }
    __builtin_amdgcn_s_setprio(0);

    // ---- B2: all B-reads of tile t complete block-wide ----
    SCHED();
    CFENCE();
    SBAR();
    SCHED();

    // ---- stage B(t+2) into buf(t) B; MFMA Q4 (m0-3, n2-3) ----
    if (pf) STAGE_B(bo + sbase, kk2);
    __builtin_amdgcn_s_setprio(1);
#pragma unroll
    for (int m = 0; m < 4; ++m)
#pragma unroll
      for (int n = 0; n < 2; ++n) {
        MFMA_(acc[m][n + 2], af0[m][0], bf1[n][0]);
        MFMA_(acc[m][n + 2], af0[m][1], bf1[n][1]);
      }
    __builtin_amdgcn_s_setprio(0);

    // ---- B3: tile boundary. Per-wave counted wait for tile t+1's stages
    //      (8 newer loads = tile t+2 in flight), then block-wide barrier so
    //      every wave sees ALL waves' t+1 data before reading it. ----
    if (t < NT - 2)
      asm volatile("s_waitcnt vmcnt(8)" ::: "memory");
    else
      asm volatile("s_waitcnt vmcnt(0)" ::: "memory");
    SBAR();
  }

  // ---- epilogue: C = acc*scale[col] + bias[col] ----
  // C/D layout (16x16x32 bf16): col = lane&15, row = quad*4 + reg.
#pragma unroll
  for (int n = 0; n < 4; ++n) {
    const int col = n0 + wc * 64 + n * 16 + lrow;
    const float s = scales[col];
    const float b = bias[col];
#pragma unroll
    for (int m = 0; m < 8; ++m) {
      const int rbase = m0 + wr * 128 + m * 16 + quad * 4;
#pragma unroll
      for (int r = 0; r < 4; ++r)
        C[(size_t)(rbase + r) * N_DIM + col] = acc[m][n][r] * s + b;
    }
  }
}

extern "C" void kernel_launch(void* const* d_in, const int* in_sizes, int n_in,
                              void* d_out, int out_size, void* d_ws, size_t ws_size,
                              hipStream_t stream) {
  const float* x    = (const float*)d_in[0];  // [4,4096,2048] fp32
  const float* w    = (const float*)d_in[1];  // [2048,2048]   fp32
  const float* bias = (const float*)d_in[2];  // [2048]        fp32
  float* out = (float*)d_out;                 // [16384,2048]  fp32

  // ws layout: xb bf16 [M*K] (64 MiB) | qw bf16 [N*K] (8 MiB) | scales fp32 [N]
  __hip_bfloat16* xb = (__hip_bfloat16*)d_ws;
  __hip_bfloat16* qw = (__hip_bfloat16*)((char*)d_ws + (size_t)M_DIM * K_DIM * 2);
  float* scales = (float*)((char*)d_ws + (size_t)M_DIM * K_DIM * 2 + (size_t)N_DIM * K_DIM * 2);

  cvt_x_k<<<dim3((M_DIM * (size_t)K_DIM) / (256 * 8)), dim3(256), 0, stream>>>(x, xb);
  ternarize_k<<<dim3(N_DIM), dim3(256), 0, stream>>>(w, qw, scales);
  gemm_bt_k<<<dim3((M_DIM / BM) * (N_DIM / BN)), dim3(512), 0, stream>>>(xb, qw, scales, bias, out);
}

// Round 4
// 352.816 us; speedup vs baseline: 1.0467x; 1.0071x over previous
//
#include <hip/hip_runtime.h>
#include <hip/hip_bf16.h>
#include <stdint.h>

// Problem (all fp32 I/O): out[m,o] = sum_k x[m,k] * qw[o,k] + bias[o]
//   qw = ternarize(weight): scale_o = max(max_k |w[o,k]|, 1e-6);
//   t = (w/scale > .5 ? 1 : w/scale < -.5 ? -1 : 0); qw = t*scale.
// Ternary t exact in bf16; scale fp32 in GEMM epilogue.
// M=16384, N=2048, K=2048.
//
// Pass C: 256x256 tile, BK=64, 8 waves, READ-AHEAD pipeline. Quadrant order
// c1(af0*bf0) c2(af0*bf1) c3(af1*bf1) c4(af1*bf0) makes every fragment's two
// uses cyclically adjacent, so each is refilled one cluster before use:
//   c1: issue bf1(t), af1h1(t)            ; MFMA c1
//   c2: issue af1h2(t); lgkm(8); BAR; STAGE_B(t+2); MFMA c2
//   c3: vmcnt(pf?4:0); lgkm(0); BAR; STAGE_A(t+2); issue af0(t+1); MFMA c3
//   c4: issue bf0(t+1)                    ; MFMA c4 ; bf0 <- bf0n
// ds_reads fly UNDER the MFMA clusters (compiler emits counted lgkm before
// each cluster for 8-12 outstanding). 2 barriers/tile. vmcnt never 0 in
// steady state. Last-tile lookahead reads are stale-but-in-bounds, unused.

#define M_DIM 16384
#define N_DIM 2048
#define K_DIM 2048

#define BM 256
#define BN 256
#define BK 64
#define NT (K_DIM / BK)  // 32 K-tiles

typedef __bf16 bf16x8 __attribute__((ext_vector_type(8)));
typedef float f32x4 __attribute__((ext_vector_type(4)));

// ---------------------------------------------------------------------------
// Pass A: x fp32 -> bf16. 8 elements/thread, float4 loads, 16 B store.
// ---------------------------------------------------------------------------
__global__ __launch_bounds__(256) void cvt_x_k(
    const float* __restrict__ x, __hip_bfloat16* __restrict__ xb) {
  const size_t i = ((size_t)blockIdx.x * 256 + threadIdx.x) * 8;
  const float4 a = *(const float4*)(x + i);
  const float4 b = *(const float4*)(x + i + 4);
  bf16x8 o;
  o[0] = (__bf16)a.x; o[1] = (__bf16)a.y; o[2] = (__bf16)a.z; o[3] = (__bf16)a.w;
  o[4] = (__bf16)b.x; o[5] = (__bf16)b.y; o[6] = (__bf16)b.z; o[7] = (__bf16)b.w;
  *(bf16x8*)((__bf16*)xb + i) = o;
}

// ---------------------------------------------------------------------------
// Pass B: per-row ternarize (fp32 in, bf16 ternary out, fp32 scale).
// ---------------------------------------------------------------------------
__global__ __launch_bounds__(256) void ternarize_k(
    const float* __restrict__ w,
    __hip_bfloat16* __restrict__ qw,
    float* __restrict__ scales) {
  const int row = blockIdx.x;
  const float* wr = w + (size_t)row * K_DIM;

  float m = 0.0f;
  for (int k = threadIdx.x; k < K_DIM; k += 256)
    m = fmaxf(m, fabsf(wr[k]));

  for (int off = 32; off > 0; off >>= 1)
    m = fmaxf(m, __shfl_down(m, off, 64));
  __shared__ float wmax[4];
  if ((threadIdx.x & 63) == 0) wmax[threadIdx.x >> 6] = m;
  __syncthreads();
  float scale = fmaxf(fmaxf(wmax[0], wmax[1]), fmaxf(wmax[2], wmax[3]));
  scale = fmaxf(scale, 1e-6f);
  if (threadIdx.x == 0) scales[row] = scale;

  for (int k = threadIdx.x; k < K_DIM; k += 256) {
    const float v = wr[k] / scale;  // identical fp32 op to the reference
    const float t = (v > 0.5f) ? 1.0f : ((v < -0.5f) ? -1.0f : 0.0f);
    qw[(size_t)row * K_DIM + k] = __float2bfloat16(t);
  }
}

// ---------------------------------------------------------------------------
// Pass C: 256x256 bf16 MFMA GEMM, read-ahead pipeline.
// ---------------------------------------------------------------------------
static __device__ __forceinline__ void gload16(const __hip_bfloat16* g,
                                               char* l) {
  // LDS dest is wave-uniform base; HW adds lane*16.
  __builtin_amdgcn_global_load_lds(
      (__attribute__((address_space(1))) void*)const_cast<__hip_bfloat16*>(g),
      (__attribute__((address_space(3))) void*)(l), 16, 0, 0);
}

#define MFMA_(d, a, b) \
  d = __builtin_amdgcn_mfma_f32_16x16x32_bf16(a, b, d, 0, 0, 0)

#define SBAR()  __builtin_amdgcn_s_barrier()
#define SCHED() __builtin_amdgcn_sched_barrier(0)

__global__ __launch_bounds__(512, 2) void gemm_bt_k(
    const __hip_bfloat16* __restrict__ A,   // xb [M,K] bf16
    const __hip_bfloat16* __restrict__ B,   // qw [N,K] bf16 ternary
    const float* __restrict__ scales,       // [N]
    const float* __restrict__ bias,         // [N]
    float* __restrict__ C) {                // [M,N] fp32
  // LDS map (bytes): buf(t&1)*65536 + { A: half*16384 | B: 32768 + half*16384 }
  // Physical chunk p (16 B) at p*16; p = row*8 + pc; data there is logical
  // column (pc ^ (row&7)) of that row (source-side swizzle); reads XOR back.
  __shared__ __align__(128) char lds[131072];

  const int tid  = threadIdx.x;
  const int wave = tid >> 6;
  const int lane = tid & 63;
  const int quad = lane >> 4;
  const int lrow = lane & 15;
  const int wr = wave >> 2;  // 0..1 (M)
  const int wc = wave & 3;   // 0..3 (N)

  // T1: XCD swizzle. 512 blocks = 8 XCDs x 64; each XCD gets an 8x8 supertile.
  const int orig = blockIdx.x;
  const int wg = (orig & 7) * 64 + (orig >> 3);
  const int bx = wg & 7;   // N blocks (8)
  const int by = wg >> 3;  // M blocks (64)
  const int m0 = by * BM;
  const int n0 = bx * BN;

  // ---- staging addresses (this thread stages rows srow+{0,64,128,192}) ----
  const int srow  = tid >> 3;                 // 0..63
  const int scol8 = (tid & 7) ^ (srow & 7);   // inverse-swizzled source chunk
  const __hip_bfloat16* Ag = A + (size_t)(m0 + srow) * K_DIM + scol8 * 8;
  const __hip_bfloat16* Bg = B + (size_t)(n0 + srow) * K_DIM + scol8 * 8;
  const int sbase = wave * 1024;  // wave-uniform chunk base within a half

  // ---- fragment-read integer offsets (tile-invariant) ----
  const int axor = lrow & 7;
  const int cs0 = ((0 + quad) ^ axor) * 16;   // k-half 0 chunk byte
  const int cs1 = ((4 + quad) ^ axor) * 16;   // k-half 1 chunk byte
  const int aHalf = wr * 16384;
  const int bHalf = 32768 + (wc >> 1) * 16384;
  const int bRow  = (wc & 1) * 64 + lrow;
  const int oA0 = aHalf + lrow * 128 + cs0;
  const int oA1 = aHalf + lrow * 128 + cs1;
  const int oB0 = bHalf + bRow * 128 + cs0;
  const int oB1 = bHalf + bRow * 128 + cs1;

  auto STAGE_A = [&](int dst, int kk) {
    const __hip_bfloat16* g = Ag + kk;
    gload16(g,               lds + dst);
    gload16(g +  64 * K_DIM, lds + dst + 8192);
    gload16(g + 128 * K_DIM, lds + dst + 16384);
    gload16(g + 192 * K_DIM, lds + dst + 24576);
  };
  auto STAGE_B = [&](int dst, int kk) {
    const __hip_bfloat16* g = Bg + kk;
    gload16(g,               lds + dst + 32768);
    gload16(g +  64 * K_DIM, lds + dst + 40960);
    gload16(g + 128 * K_DIM, lds + dst + 49152);
    gload16(g + 192 * K_DIM, lds + dst + 57344);
  };

  f32x4 acc[8][4] = {};
  bf16x8 af0[4][2], af1[4][2], bf0[2][2], bf0n[2][2], bf1[2][2];

  // ---- prologue: stage tiles 0 (buf0) and 1 (buf1); wait tile 0;
  //      pre-read af0(0), bf0(0) so c1 of tile 0 has its operands ----
  STAGE_A(sbase, 0);          STAGE_B(sbase, 0);
  STAGE_A(sbase + 65536, BK); STAGE_B(sbase + 65536, BK);
  asm volatile("s_waitcnt vmcnt(8)" ::: "memory");  // tile 0 landed
  SBAR();
#pragma unroll
  for (int m = 0; m < 4; ++m) {
    af0[m][0] = *(const bf16x8*)(lds + oA0 + m * 2048);
    af0[m][1] = *(const bf16x8*)(lds + oA1 + m * 2048);
  }
#pragma unroll
  for (int n = 0; n < 2; ++n) {
    bf0[n][0] = *(const bf16x8*)(lds + oB0 + n * 2048);
    bf0[n][1] = *(const bf16x8*)(lds + oB1 + n * 2048);
  }

  for (int t = 0; t < NT; ++t) {
    const int bo  = (t & 1) << 16;   // current buffer
    const int nbo = bo ^ 65536;      // next buffer
    const int kk2 = (t + 2) * BK;
    const bool pf = (t + 2) < NT;

    // ---- c1: issue bf1(t) then af1h1(t); MFMA (m0-3 x n0-1) af0*bf0 ----
#pragma unroll
    for (int n = 0; n < 2; ++n) {
      bf1[n][0] = *(const bf16x8*)(lds + bo + oB0 + (n + 2) * 2048);
      bf1[n][1] = *(const bf16x8*)(lds + bo + oB1 + (n + 2) * 2048);
    }
    SCHED();  // pin bf1 issue before af1h1 (counted lgkm at c2 relies on it)
#pragma unroll
    for (int m = 0; m < 2; ++m) {
      af1[m][0] = *(const bf16x8*)(lds + bo + oA0 + (m + 4) * 2048);
      af1[m][1] = *(const bf16x8*)(lds + bo + oA1 + (m + 4) * 2048);
    }
    SCHED();
    __builtin_amdgcn_s_setprio(1);
#pragma unroll
    for (int m = 0; m < 4; ++m)
#pragma unroll
      for (int n = 0; n < 2; ++n) {
        MFMA_(acc[m][n], af0[m][0], bf0[n][0]);
        MFMA_(acc[m][n], af0[m][1], bf0[n][1]);
      }
    __builtin_amdgcn_s_setprio(0);
    SCHED();

    // ---- c2: issue af1h2(t); lgkm(8) [bf1 landed, 8 af1 may fly]; BAR;
    //          STAGE_B(t+2) -> buf bo; MFMA (m0-3 x n2-3) af0*bf1 ----
#pragma unroll
    for (int m = 2; m < 4; ++m) {
      af1[m][0] = *(const bf16x8*)(lds + bo + oA0 + (m + 4) * 2048);
      af1[m][1] = *(const bf16x8*)(lds + bo + oA1 + (m + 4) * 2048);
    }
    SCHED();
    asm volatile("s_waitcnt lgkmcnt(8)" ::: "memory");  // all B-reads of buf bo done
    SBAR();  // -> safe to overwrite buf bo B-region
    if (pf) STAGE_B(bo + sbase, kk2);
    SCHED();
    __builtin_amdgcn_s_setprio(1);
#pragma unroll
    for (int m = 0; m < 4; ++m)
#pragma unroll
      for (int n = 0; n < 2; ++n) {
        MFMA_(acc[m][n + 2], af0[m][0], bf1[n][0]);
        MFMA_(acc[m][n + 2], af0[m][1], bf1[n][1]);
      }
    __builtin_amdgcn_s_setprio(0);
    SCHED();

    // ---- c3: vmcnt ensures A(t+1),B(t+1) landed (allow B(t+2) in flight);
    //          lgkm(0) = all A-reads of buf bo done; BAR; STAGE_A(t+2);
    //          issue af0(t+1) from buf nbo; MFMA (m4-7 x n2-3) af1*bf1 ----
    if (pf)
      asm volatile("s_waitcnt vmcnt(4)" ::: "memory");
    else
      asm volatile("s_waitcnt vmcnt(0)" ::: "memory");
    asm volatile("s_waitcnt lgkmcnt(0)" ::: "memory");
    SBAR();  // -> buf bo A-region overwrite safe; buf nbo (tile t+1) readable
    if (pf) STAGE_A(bo + sbase, kk2);
#pragma unroll
    for (int m = 0; m < 4; ++m) {
      af0[m][0] = *(const bf16x8*)(lds + nbo + oA0 + m * 2048);
      af0[m][1] = *(const bf16x8*)(lds + nbo + oA1 + m * 2048);
    }
    SCHED();
    __builtin_amdgcn_s_setprio(1);
#pragma unroll
    for (int m = 0; m < 4; ++m)
#pragma unroll
      for (int n = 0; n < 2; ++n) {
        MFMA_(acc[m + 4][n + 2], af1[m][0], bf1[n][0]);
        MFMA_(acc[m + 4][n + 2], af1[m][1], bf1[n][1]);
      }
    __builtin_amdgcn_s_setprio(0);
    SCHED();

    // ---- c4: issue bf0(t+1) from buf nbo; MFMA (m4-7 x n0-1) af1*bf0 ----
#pragma unroll
    for (int n = 0; n < 2; ++n) {
      bf0n[n][0] = *(const bf16x8*)(lds + nbo + oB0 + n * 2048);
      bf0n[n][1] = *(const bf16x8*)(lds + nbo + oB1 + n * 2048);
    }
    SCHED();
    __builtin_amdgcn_s_setprio(1);
#pragma unroll
    for (int m = 0; m < 4; ++m)
#pragma unroll
      for (int n = 0; n < 2; ++n) {
        MFMA_(acc[m + 4][n], af1[m][0], bf0[n][0]);
        MFMA_(acc[m + 4][n], af1[m][1], bf0[n][1]);
      }
    __builtin_amdgcn_s_setprio(0);
    SCHED();
    // rotate bf0 <- bf0n (SSA copy; regalloc coalesces)
#pragma unroll
    for (int n = 0; n < 2; ++n) {
      bf0[n][0] = bf0n[n][0];
      bf0[n][1] = bf0n[n][1];
    }
  }

  // ---- epilogue: C = acc*scale[col] + bias[col] ----
  // C/D layout (16x16x32 bf16): col = lane&15, row = quad*4 + reg.
#pragma unroll
  for (int n = 0; n < 4; ++n) {
    const int col = n0 + wc * 64 + n * 16 + lrow;
    const float s = scales[col];
    const float b = bias[col];
#pragma unroll
    for (int m = 0; m < 8; ++m) {
      const int rbase = m0 + wr * 128 + m * 16 + quad * 4;
#pragma unroll
      for (int r = 0; r < 4; ++r)
        C[(size_t)(rbase + r) * N_DIM + col] = acc[m][n][r] * s + b;
    }
  }
}

extern "C" void kernel_launch(void* const* d_in, const int* in_sizes, int n_in,
                              void* d_out, int out_size, void* d_ws, size_t ws_size,
                              hipStream_t stream) {
  const float* x    = (const float*)d_in[0];  // [4,4096,2048] fp32
  const float* w    = (const float*)d_in[1];  // [2048,2048]   fp32
  const float* bias = (const float*)d_in[2];  // [2048]        fp32
  float* out = (float*)d_out;                 // [16384,2048]  fp32

  // ws layout: xb bf16 [M*K] (64 MiB) | qw bf16 [N*K] (8 MiB) | scales fp32 [N]
  __hip_bfloat16* xb = (__hip_bfloat16*)d_ws;
  __hip_bfloat16* qw = (__hip_bfloat16*)((char*)d_ws + (size_t)M_DIM * K_DIM * 2);
  float* scales = (float*)((char*)d_ws + (size_t)M_DIM * K_DIM * 2 + (size_t)N_DIM * K_DIM * 2);

  cvt_x_k<<<dim3((M_DIM * (size_t)K_DIM) / (256 * 8)), dim3(256), 0, stream>>>(x, xb);
  ternarize_k<<<dim3(N_DIM), dim3(256), 0, stream>>>(w, qw, scales);
  gemm_bt_k<<<dim3((M_DIM / BM) * (N_DIM / BN)), dim3(512), 0, stream>>>(xb, qw, scales, bias, out);
}